// Round 6
// baseline (231.103 us; speedup 1.0000x reference)
//
#include <hip/hip_runtime.h>
#include <cstdint>
#include <cstddef>

// Block-diagonal GRU on MI355X (gfx950), fully fused bf16 MFMA path.
// B=8192, IN=1024, H=2048, NB=8, BS=256, 3H=6144.
// Fused kernel: wx (K=1024) + wh (K=256, block-diag) for a 128x64 h-tile,
// gates in epilogue. 32x32x16 MFMA, fragment-linear LDS (zero-conflict,
// zero read-side addr math), counted vmcnt, compiler-counted lgkm waits.

typedef __attribute__((ext_vector_type(8))) short bf16x8;
typedef __attribute__((ext_vector_type(16))) float f32x16;

__device__ __forceinline__ unsigned short f2bf(float f) {
    uint32_t u = __float_as_uint(f);
    u += 0x7FFFu + ((u >> 16) & 1u);   // round-to-nearest-even
    return (unsigned short)(u >> 16);
}
__device__ __forceinline__ float bf2f(unsigned short b) {
    return __uint_as_float(((uint32_t)b) << 16);
}

__device__ __forceinline__ void gload16(const void* g, void* l) {
    __builtin_amdgcn_global_load_lds(
        (const __attribute__((address_space(1))) void*)g,
        (__attribute__((address_space(3))) void*)l,
        16, 0, 0);
}

__device__ __forceinline__ float sigmoidf_(float x) {
    return 1.0f / (1.0f + __expf(-x));
}
__device__ __forceinline__ float tanhf_(float x) {
    float e = __expf(-2.0f * fabsf(x));
    float t = (1.0f - e) / (1.0f + e);
    return copysignf(t, x);
}

// ---------------------------------------------------------------- one cast
// regions (in float4 units): x 2097152 | W_ir 1572864 | h 4194304 | W_h 393216
__global__ __launch_bounds__(256)
void cast_all(const float* __restrict__ x, const float* __restrict__ wir,
              const float* __restrict__ h, const float* __restrict__ wh,
              unsigned short* __restrict__ xb, unsigned short* __restrict__ wirb,
              unsigned short* __restrict__ hb, unsigned short* __restrict__ whb) {
    const int i = blockIdx.x * 256 + threadIdx.x;
    const float* s; unsigned short* d; int j;
    if (i < 2097152)      { s = x;   d = xb;   j = i; }
    else if (i < 3670016) { s = wir; d = wirb; j = i - 2097152; }
    else if (i < 7864320) { s = h;   d = hb;   j = i - 3670016; }
    else                  { s = wh;  d = whb;  j = i - 7864320; }
    const float4 v = *reinterpret_cast<const float4*>(s + (size_t)j * 4);
    ushort4 o;
    o.x = f2bf(v.x); o.y = f2bf(v.y); o.z = f2bf(v.z); o.w = f2bf(v.w);
    *reinterpret_cast<ushort4*>(d + (size_t)j * 4) = o;
}

// ---------------------------------------------------------------- fused GRU
// 256 thr (4 waves, 2M x 2N). Block tile: 128 rows x 64 h-cols x 3 strips.
// 20 K-tiles (BK=64): 0..15 phase1 (x @ W_ir^T), 16..19 phase2 (hb @ W_h^T).
// acc[4][2] f32x16: groups 0=r(sum), 1=z(sum), 2=wxn, 3=whn; mi = 32-row frag.
// LDS fragment-linear: frag(idx) = 512 elems at idx*512, lane-linear (lane*8).
//   A frags: idx = m*4 + kk (m 0..3 row-grp of 32, kk 0..3 of K=16)  -> 16 KiB
//   B frags: idx = g*4 + kk (g = strip*2 + half, 6 row-grps)          -> 24 KiB
// Staging: wave w stages kk=w of every row-group; per-lane global source =
// (row-grp + lane&31) row, k-offset w*16 + (lane>>5)*8. 10 issues/thread/tile
// in groups 4+4+2; steady-state wait vmcnt(4) once per K-tile; peel vmcnt(0).
// 32x32x16 layouts: A row=lane&31, k=(lane>>5)*8+j ; B col=lane&31 same k;
// C/D col=lane&31, row=(reg&3)+8*(reg>>2)+4*(lane>>5)  [m74/m101 verified].

#define IG(ptr, kt, dstbase) gload16((ptr) + (size_t)(kt) * 64, (dstbase) + doff)

#define I0_1(kt, ds) do { IG(pB1[0], kt, Bs + (ds) * 12288 + 0 * 2048); \
                          IG(pB1[1], kt, Bs + (ds) * 12288 + 1 * 2048); \
                          IG(pB1[2], kt, Bs + (ds) * 12288 + 2 * 2048); \
                          IG(pB1[3], kt, Bs + (ds) * 12288 + 3 * 2048); } while (0)
#define I1_1(kt, ds) do { IG(pB1[4], kt, Bs + (ds) * 12288 + 4 * 2048); \
                          IG(pB1[5], kt, Bs + (ds) * 12288 + 5 * 2048); \
                          IG(pA1[0], kt, As + (ds) * 8192 + 0 * 2048);  \
                          IG(pA1[1], kt, As + (ds) * 8192 + 1 * 2048); } while (0)
#define I2_1(kt, ds) do { IG(pA1[2], kt, As + (ds) * 8192 + 2 * 2048);  \
                          IG(pA1[3], kt, As + (ds) * 8192 + 3 * 2048); } while (0)
#define I0_2(kt, ds) do { IG(pB2[0], kt, Bs + (ds) * 12288 + 0 * 2048); \
                          IG(pB2[1], kt, Bs + (ds) * 12288 + 1 * 2048); \
                          IG(pB2[2], kt, Bs + (ds) * 12288 + 2 * 2048); \
                          IG(pB2[3], kt, Bs + (ds) * 12288 + 3 * 2048); } while (0)
#define I1_2(kt, ds) do { IG(pB2[4], kt, Bs + (ds) * 12288 + 4 * 2048); \
                          IG(pB2[5], kt, Bs + (ds) * 12288 + 5 * 2048); \
                          IG(pA2[0], kt, As + (ds) * 8192 + 0 * 2048);  \
                          IG(pA2[1], kt, As + (ds) * 8192 + 1 * 2048); } while (0)
#define I2_2(kt, ds) do { IG(pA2[2], kt, As + (ds) * 8192 + 2 * 2048);  \
                          IG(pA2[3], kt, As + (ds) * 8192 + 3 * 2048); } while (0)

#define LDA32(mi, kk) (*(const bf16x8*)(aS + ((wm * 2 + (mi)) * 4 + (kk)) * 512 + l8))
#define LDB32(s, kk)  (*(const bf16x8*)(bS + (((s) * 2 + wn) * 4 + (kk)) * 512 + l8))

#define RDHALF(h_) do { \
    av[0][0] = LDA32(0, 2 * (h_));     av[1][0] = LDA32(1, 2 * (h_));     \
    bv[0][0] = LDB32(0, 2 * (h_));     bv[1][0] = LDB32(1, 2 * (h_));     \
    bv[2][0] = LDB32(2, 2 * (h_));                                        \
    av[0][1] = LDA32(0, 2 * (h_) + 1); av[1][1] = LDA32(1, 2 * (h_) + 1); \
    bv[0][1] = LDB32(0, 2 * (h_) + 1); bv[1][1] = LDB32(1, 2 * (h_) + 1); \
    bv[2][1] = LDB32(2, 2 * (h_) + 1); } while (0)

#define FMA6(kl, NT) do { \
    acc[0][0]  = __builtin_amdgcn_mfma_f32_32x32x16_bf16(av[0][kl], bv[0][kl], acc[0][0], 0, 0, 0);  \
    acc[0][1]  = __builtin_amdgcn_mfma_f32_32x32x16_bf16(av[1][kl], bv[0][kl], acc[0][1], 0, 0, 0);  \
    acc[1][0]  = __builtin_amdgcn_mfma_f32_32x32x16_bf16(av[0][kl], bv[1][kl], acc[1][0], 0, 0, 0);  \
    acc[1][1]  = __builtin_amdgcn_mfma_f32_32x32x16_bf16(av[1][kl], bv[1][kl], acc[1][1], 0, 0, 0);  \
    acc[NT][0] = __builtin_amdgcn_mfma_f32_32x32x16_bf16(av[0][kl], bv[2][kl], acc[NT][0], 0, 0, 0); \
    acc[NT][1] = __builtin_amdgcn_mfma_f32_32x32x16_bf16(av[1][kl], bv[2][kl], acc[NT][1], 0, 0, 0); \
} while (0)

#define KSTEP(slot_, I0, W0, I1, I2, NT) do {                                  \
    const unsigned short* aS = As + (slot_) * 8192;                            \
    const unsigned short* bS = Bs + (slot_) * 12288;                           \
    I0;                                                                        \
    asm volatile("s_waitcnt vmcnt(" W0 ")" ::: "memory");                      \
    __builtin_amdgcn_s_barrier();                                              \
    RDHALF(0);                                                                 \
    I1;                                                                        \
    __builtin_amdgcn_s_setprio(1); FMA6(0, NT); FMA6(1, NT);                   \
    __builtin_amdgcn_s_setprio(0);                                             \
    RDHALF(1);                                                                 \
    I2;                                                                        \
    __builtin_amdgcn_s_setprio(1); FMA6(0, NT); FMA6(1, NT);                   \
    __builtin_amdgcn_s_setprio(0);                                             \
    __builtin_amdgcn_s_barrier();                                              \
} while (0)

__global__ __launch_bounds__(256, 2)
void gru_fused(const unsigned short* __restrict__ Xb,    // [8192][1024] bf16
               const unsigned short* __restrict__ Wirb,  // [6144][1024] bf16
               const unsigned short* __restrict__ Hbb,   // [8192][2048] bf16
               const unsigned short* __restrict__ Whb,   // [8][768][256] bf16
               const float* __restrict__ b_ir_lin,       // [6144]
               const float* __restrict__ b_ir,           // [6144]
               const float* __restrict__ b_hr,           // [6144]
               float* __restrict__ out) {                // [8192][2048] f32
    constexpr int K1 = 1024, H = 2048;
    __shared__ unsigned short lds[2 * 8192 + 2 * 12288];   // 80 KiB
    unsigned short* const As = lds;
    unsigned short* const Bs = lds + 2 * 8192;

    const int tid  = threadIdx.x;
    const int lane = tid & 63;
    const int w    = tid >> 6;   // 0..3; also the kk this wave stages
    const int wm   = w >> 1;     // 0..1 (64-row half)
    const int wn   = w & 1;      // 0..1 (32-col half)
    const int l31  = lane & 31;
    const int lhi  = lane >> 5;
    const int l8   = lane * 8;   // lane-linear fragment slot (elems)

    // Grid: 2048 = 8 kb (XCD-exclusive) x 64 bm x 4 hsub (hsub innermost).
    const int bid  = blockIdx.x;
    const int kb   = bid & 7;
    const int idx  = bid >> 3;
    const int bm   = (idx >> 2) * 128;
    const int hsub = idx & 3;
    const int hcb  = kb * 256 + hsub * 64;   // h-column base

    // ---- per-lane staging sources (fragment-gather form)
    const int kof  = w * 16 + lhi * 8;       // k-elem offset within 64-wide tile
    const int doff = w * 512 + l8;           // dest: frag (grp*4 + w), lane slot
    const unsigned short* pA1[4];
    const unsigned short* pA2[4];
    #pragma unroll
    for (int j = 0; j < 4; ++j) {
        pA1[j] = Xb  + (size_t)(bm + j * 32 + l31) * K1 + kof;
        pA2[j] = Hbb + (size_t)(bm + j * 32 + l31) * H + kb * 256 + kof;
    }
    const unsigned short* pB1[6];
    const unsigned short* pB2[6];
    #pragma unroll
    for (int g = 0; g < 6; ++g) {
        const int s = g >> 1, hf = (g & 1) * 32;
        pB1[g] = Wirb + (size_t)(s * 2048 + hcb + hf + l31) * K1 + kof;
        pB2[g] = Whb + (size_t)kb * 196608
                     + (size_t)(s * 256 + hsub * 64 + hf + l31) * 256 + kof;
    }

    f32x16 acc[4][2] = {};   // [r, z, wxn, whn][mi]
    bf16x8 av[2][2], bv[3][2];

    // ---- prologue: tile 0 (phase1)
    I0_1(0, 0); I1_1(0, 0); I2_1(0, 0);

    // ---- phase1: tiles 0..14
    #pragma unroll 1
    for (int t = 0; t < 15; ++t) {
        const int sl = t & 1, nx = sl ^ 1;
        KSTEP(sl, I0_1(t + 1, nx), "4", I1_1(t + 1, nx), I2_1(t + 1, nx), 2);
    }
    // ---- bridge: compute tile 15 (phase1), issue tile 16 (phase2 k2=0)
    KSTEP(1, I0_2(0, 0), "4", I1_2(0, 0), I2_2(0, 0), 2);
    // ---- phase2: tiles 16..18
    #pragma unroll 1
    for (int t = 16; t < 19; ++t) {
        const int sl = t & 1, nx = sl ^ 1;
        KSTEP(sl, I0_2(t - 15, nx), "4", I1_2(t - 15, nx), I2_2(t - 15, nx), 3);
    }
    // ---- peel: tile 19, drain
    KSTEP(1, ((void)0), "0", ((void)0), ((void)0), 3);

    // ---- gate epilogue (h read as bf16; C/D: col=l31, row=(r&3)+8*(r>>2)+4*lhi)
    const int hcol = hcb + wn * 32 + l31;
    const int lcol = hcol & 255;
    const float bir0 = b_ir_lin[hcol]        + b_ir[hcol];
    const float bir1 = b_ir_lin[2048 + hcol] + b_ir[2048 + hcol];
    const float bir2 = b_ir_lin[4096 + hcol] + b_ir[4096 + hcol];
    const float bhr0 = b_hr[kb * 768 + lcol];
    const float bhr1 = b_hr[kb * 768 + 256 + lcol];
    const float bhr2 = b_hr[kb * 768 + 512 + lcol];
    #pragma unroll
    for (int mi = 0; mi < 2; ++mi) {
        #pragma unroll
        for (int r = 0; r < 16; ++r) {
            const int row = bm + wm * 64 + mi * 32 + (r & 3) + 8 * (r >> 2) + 4 * lhi;
            const float pr = acc[0][mi][r] + bir0 + bhr0;
            const float pz = acc[1][mi][r] + bir1 + bhr1;
            const float xn = acc[2][mi][r] + bir2;
            const float hn = acc[3][mi][r] + bhr2;
            const float rg = sigmoidf_(pr);
            const float zg = sigmoidf_(pz);
            const float ng = tanhf_(xn + rg * hn);
            const float hv = bf2f(Hbb[(size_t)row * H + hcol]);
            out[(size_t)row * H + hcol] = (1.0f - zg) * hv + zg * ng;
        }
    }
}

// ---------------------------------------------------------------- launch
extern "C" void kernel_launch(void* const* d_in, const int* in_sizes, int n_in,
                              void* d_out, int out_size, void* d_ws, size_t ws_size,
                              hipStream_t stream) {
    const float* x        = (const float*)d_in[0];
    const float* h        = (const float*)d_in[1];
    const float* W_ir     = (const float*)d_in[2];
    const float* b_ir_lin = (const float*)d_in[3];
    const float* b_ir     = (const float*)d_in[4];
    const float* W_h      = (const float*)d_in[5];
    const float* b_hr     = (const float*)d_in[6];
    float* out = (float*)d_out;

    char* ws = (char*)d_ws;
    unsigned short* xb   = (unsigned short*)(ws);               // 16 MiB
    unsigned short* wirb = (unsigned short*)(ws + 16777216);    // 12 MiB
    unsigned short* hb   = (unsigned short*)(ws + 29360128);    // 32 MiB
    unsigned short* whb  = (unsigned short*)(ws + 62914560);    //  3 MiB

    cast_all<<<32256, 256, 0, stream>>>(x, W_ir, h, W_h, xb, wirb, hb, whb);

    gru_fused<<<2048, 256, 0, stream>>>(xb, wirb, hb, whb,
                                        b_ir_lin, b_ir, b_hr, out);
}

// Round 7
// 170.553 us; speedup vs baseline: 1.3550x; 1.3550x over previous
//
#include <hip/hip_runtime.h>
#include <cstdint>
#include <cstddef>

// Block-diagonal GRU on MI355X (gfx950), fully fused bf16 MFMA path.
// B=8192, IN=1024, H=2048, NB=8, BS=256, 3H=6144.
// One kernel computes wx (K=1024) AND wh (K=256, block-diagonal) for a
// 128x64 h-column tile, then applies the GRU gates in the epilogue.
// Geometry: 256 thr (4 waves 2Mx2N), BM=128, BK=64, LDS 80 KiB -> 2 blocks/CU.
// K-step: 2 phases x {10 ds_read_b128 | stage | bar | lgkm0 | 24 MFMA | bar},
// one counted vmcnt(4) per K-tile (never 0 until peel).

typedef __attribute__((ext_vector_type(8))) short bf16x8;
typedef __attribute__((ext_vector_type(4))) float f32x4;

__device__ __forceinline__ unsigned short f2bf(float f) {
    uint32_t u = __float_as_uint(f);
    u += 0x7FFFu + ((u >> 16) & 1u);   // round-to-nearest-even
    return (unsigned short)(u >> 16);
}
__device__ __forceinline__ float bf2f(unsigned short b) {
    return __uint_as_float(((uint32_t)b) << 16);
}

__device__ __forceinline__ void gload16(const void* g, void* l) {
    __builtin_amdgcn_global_load_lds(
        (const __attribute__((address_space(1))) void*)g,
        (__attribute__((address_space(3))) void*)l,
        16, 0, 0);
}

__device__ __forceinline__ float sigmoidf_(float x) {
    return 1.0f / (1.0f + __expf(-x));
}
__device__ __forceinline__ float tanhf_(float x) {
    float e = __expf(-2.0f * fabsf(x));
    float t = (1.0f - e) / (1.0f + e);
    return copysignf(t, x);
}

// ---------------------------------------------------------------- one cast
// regions (in float4 units): x 2097152 | W_ir 1572864 | h 4194304 | W_h 393216
__global__ __launch_bounds__(256)
void cast_all(const float* __restrict__ x, const float* __restrict__ wir,
              const float* __restrict__ h, const float* __restrict__ wh,
              unsigned short* __restrict__ xb, unsigned short* __restrict__ wirb,
              unsigned short* __restrict__ hb, unsigned short* __restrict__ whb) {
    const int i = blockIdx.x * 256 + threadIdx.x;
    const float* s; unsigned short* d; int j;
    if (i < 2097152)      { s = x;   d = xb;   j = i; }
    else if (i < 3670016) { s = wir; d = wirb; j = i - 2097152; }
    else if (i < 7864320) { s = h;   d = hb;   j = i - 3670016; }
    else                  { s = wh;  d = whb;  j = i - 7864320; }
    const float4 v = *reinterpret_cast<const float4*>(s + (size_t)j * 4);
    ushort4 o;
    o.x = f2bf(v.x); o.y = f2bf(v.y); o.z = f2bf(v.z); o.w = f2bf(v.w);
    *reinterpret_cast<ushort4*>(d + (size_t)j * 4) = o;
}

// ---------------------------------------------------------------- fused GRU
// acc groups: 0=r(sum of both GEMMs), 1=z(sum), 2=wxn, 3=whn.
// NT = 2 during phase1 (x @ W_ir^T), 3 during phase2 (hb @ W_h[kb]^T).
// A tile 128x64 (4 chunks of 32 rows), B tile 192x64 (6 chunks).
// Issues/thread/K-tile: 10 = [B0..B3] + [B4,B5,A0,A1] + [A2,A3].
// LDS rows 128 B, T2 XOR-swizzle byte^=(row&7)<<4 via inverse-swizzled
// global source (linear gload_lds dest) + swizzled ds_read (G21).

#define MFMA24(NT) do {                                                        \
    asm volatile("s_waitcnt lgkmcnt(0)" ::: "memory");                         \
    __builtin_amdgcn_sched_barrier(0);                                         \
    __builtin_amdgcn_s_setprio(1);                                             \
    _Pragma("unroll")                                                          \
    for (int m_ = 0; m_ < 4; ++m_) {                                           \
        acc[0][m_][0] = __builtin_amdgcn_mfma_f32_16x16x32_bf16(               \
            av[m_], bv[0][0], acc[0][m_][0], 0, 0, 0);                         \
        acc[0][m_][1] = __builtin_amdgcn_mfma_f32_16x16x32_bf16(               \
            av[m_], bv[0][1], acc[0][m_][1], 0, 0, 0);                         \
        acc[1][m_][0] = __builtin_amdgcn_mfma_f32_16x16x32_bf16(               \
            av[m_], bv[1][0], acc[1][m_][0], 0, 0, 0);                         \
        acc[1][m_][1] = __builtin_amdgcn_mfma_f32_16x16x32_bf16(               \
            av[m_], bv[1][1], acc[1][m_][1], 0, 0, 0);                         \
        acc[NT][m_][0] = __builtin_amdgcn_mfma_f32_16x16x32_bf16(              \
            av[m_], bv[2][0], acc[NT][m_][0], 0, 0, 0);                        \
        acc[NT][m_][1] = __builtin_amdgcn_mfma_f32_16x16x32_bf16(              \
            av[m_], bv[2][1], acc[NT][m_][1], 0, 0, 0);                        \
    }                                                                          \
    __builtin_amdgcn_s_setprio(0);                                             \
} while (0)

#define LDA(m, kb_) (*(const bf16x8*)(aS + (wm * 64 + (m) * 16 + fr) * 64 + (kb_)))
#define LDB(s, n_, kb_) (*(const bf16x8*)(bS + ((s) * 64 + wn * 32 + (n_) * 16 + fr) * 64 + (kb_)))

// phase1 issue groups (kt in units of 64 elements along K=1024)
#define I0_1(kt, ds) do {                                                      \
    gload16(b1[0] + (size_t)(kt) * 64, Bs + (ds) * 12288 + 0 * 2048 + doff);   \
    gload16(b1[1] + (size_t)(kt) * 64, Bs + (ds) * 12288 + 1 * 2048 + doff);   \
    gload16(b1[2] + (size_t)(kt) * 64, Bs + (ds) * 12288 + 2 * 2048 + doff);   \
    gload16(b1[3] + (size_t)(kt) * 64, Bs + (ds) * 12288 + 3 * 2048 + doff); } while (0)
#define I1_1(kt, ds) do {                                                      \
    gload16(b1[4] + (size_t)(kt) * 64, Bs + (ds) * 12288 + 4 * 2048 + doff);   \
    gload16(b1[5] + (size_t)(kt) * 64, Bs + (ds) * 12288 + 5 * 2048 + doff);   \
    gload16(a1[0] + (size_t)(kt) * 64, As + (ds) * 8192 + 0 * 2048 + doff);    \
    gload16(a1[1] + (size_t)(kt) * 64, As + (ds) * 8192 + 1 * 2048 + doff); } while (0)
#define I2_1(kt, ds) do {                                                      \
    gload16(a1[2] + (size_t)(kt) * 64, As + (ds) * 8192 + 2 * 2048 + doff);    \
    gload16(a1[3] + (size_t)(kt) * 64, As + (ds) * 8192 + 3 * 2048 + doff); } while (0)
// phase2 issue groups (k2 in units of 64 along K=256)
#define I0_2(k2, ds) do {                                                      \
    gload16(b2[0] + (size_t)(k2) * 64, Bs + (ds) * 12288 + 0 * 2048 + doff);   \
    gload16(b2[1] + (size_t)(k2) * 64, Bs + (ds) * 12288 + 1 * 2048 + doff);   \
    gload16(b2[2] + (size_t)(k2) * 64, Bs + (ds) * 12288 + 2 * 2048 + doff);   \
    gload16(b2[3] + (size_t)(k2) * 64, Bs + (ds) * 12288 + 3 * 2048 + doff); } while (0)
#define I1_2(k2, ds) do {                                                      \
    gload16(b2[4] + (size_t)(k2) * 64, Bs + (ds) * 12288 + 4 * 2048 + doff);   \
    gload16(b2[5] + (size_t)(k2) * 64, Bs + (ds) * 12288 + 5 * 2048 + doff);   \
    gload16(a2[0] + (size_t)(k2) * 64, As + (ds) * 8192 + 0 * 2048 + doff);    \
    gload16(a2[1] + (size_t)(k2) * 64, As + (ds) * 8192 + 1 * 2048 + doff); } while (0)
#define I2_2(k2, ds) do {                                                      \
    gload16(a2[2] + (size_t)(k2) * 64, As + (ds) * 8192 + 2 * 2048 + doff);    \
    gload16(a2[3] + (size_t)(k2) * 64, As + (ds) * 8192 + 3 * 2048 + doff); } while (0)

// One K-tile:
//  I0(t+1); vmcnt(W0); bar;                 <- slot t landed
//  P0: ds kb0 (10 b128); I1(t+1); bar; lgkm0; 24 MFMA; bar;
//  P1: ds kb1 (10 b128); I2(t+1); bar; lgkm0; 24 MFMA; bar;
#define KSTEP(slot_, I0, W0, I1, I2, NT) do {                                  \
    const unsigned short* aS = As + (slot_) * 8192;                            \
    const unsigned short* bS = Bs + (slot_) * 12288;                           \
    I0;                                                                        \
    asm volatile("s_waitcnt vmcnt(" W0 ")" ::: "memory");                      \
    __builtin_amdgcn_s_barrier();                                              \
    _Pragma("unroll") for (int m_ = 0; m_ < 4; ++m_) av[m_] = LDA(m_, kb0);    \
    _Pragma("unroll") for (int s_ = 0; s_ < 3; ++s_) {                         \
        bv[s_][0] = LDB(s_, 0, kb0); bv[s_][1] = LDB(s_, 1, kb0); }            \
    I1;                                                                        \
    __builtin_amdgcn_s_barrier();                                              \
    MFMA24(NT);                                                                \
    __builtin_amdgcn_s_barrier();                                              \
    _Pragma("unroll") for (int m_ = 0; m_ < 4; ++m_) av[m_] = LDA(m_, kb1);    \
    _Pragma("unroll") for (int s_ = 0; s_ < 3; ++s_) {                         \
        bv[s_][0] = LDB(s_, 0, kb1); bv[s_][1] = LDB(s_, 1, kb1); }            \
    I2;                                                                        \
    __builtin_amdgcn_s_barrier();                                              \
    MFMA24(NT);                                                                \
    __builtin_amdgcn_s_barrier();                                              \
} while (0)

__global__ __launch_bounds__(256, 2)
void gru_fused(const unsigned short* __restrict__ Xb,    // [8192][1024] bf16
               const unsigned short* __restrict__ Wirb,  // [6144][1024] bf16
               const unsigned short* __restrict__ Hbb,   // [8192][2048] bf16
               const unsigned short* __restrict__ Whb,   // [8][768][256] bf16
               const float* __restrict__ b_ir_lin,       // [6144]
               const float* __restrict__ b_ir,           // [6144]
               const float* __restrict__ b_hr,           // [6144]
               float* __restrict__ out) {                // [8192][2048] f32
    constexpr int K1 = 1024, H = 2048;
    __shared__ unsigned short lds[2 * 8192 + 2 * 12288];   // 80 KiB
    unsigned short* const As = lds;
    unsigned short* const Bs = lds + 2 * 8192;

    const int tid  = threadIdx.x;
    const int lane = tid & 63;
    const int w    = tid >> 6;   // 0..3
    const int wm   = w >> 1;     // 0..1 (64-row half)
    const int wn   = w & 1;      // 0..1 (32-col half)

    // Grid: 2048 = 8 kb (XCD-exclusive) x 64 bm x 4 hsub (hsub innermost).
    const int bid  = blockIdx.x;
    const int kb   = bid & 7;
    const int idx  = bid >> 3;          // 0..255
    const int bm   = (idx >> 2) * 128;
    const int hsub = idx & 3;
    const int hcb  = kb * 256 + hsub * 64;   // h-column base

    // ---- staging sources (inverse-swizzled global, linear LDS dest)
    const int srow  = tid >> 3;                 // 0..31 (row within 32-row chunk)
    const int chunk = (tid & 7) ^ (srow & 7);   // T2 XOR involution
    const int scol  = chunk * 8;
    const int doff  = tid * 8;                  // element offset within a chunk
    const unsigned short* a1[4];
    const unsigned short* a2[4];
    #pragma unroll
    for (int q = 0; q < 4; ++q) {
        a1[q] = Xb  + (size_t)(bm + q * 32 + srow) * K1 + scol;
        a2[q] = Hbb + (size_t)(bm + q * 32 + srow) * H + kb * 256 + scol;
    }
    const unsigned short* b1[6];
    const unsigned short* b2[6];
    #pragma unroll
    for (int q = 0; q < 6; ++q) {
        const int s  = q >> 1;
        const int rr = (q & 1) * 32 + srow;
        b1[q] = Wirb + (size_t)(s * 2048 + hcb + rr) * K1 + scol;
        b2[q] = Whb + (size_t)kb * 196608 + (size_t)(s * 256 + hsub * 64 + rr) * 256 + scol;
    }

    // ---- fragment read offsets (swizzled reads, rows are 128 B)
    const int fr  = lane & 15;
    const int k0e = (lane >> 4) * 8;
    const int mfr = (fr & 7) << 4;
    const int kb0 = ((k0e * 2) ^ mfr) >> 1;
    const int kb1 = (((k0e * 2) + 64) ^ mfr) >> 1;

    f32x4 acc[4][4][2] = {};   // [group][m-frag][n-frag]
    bf16x8 av[4], bv[3][2];

    // ---- prologue: tile 0 (phase1)
    I0_1(0, 0); I1_1(0, 0); I2_1(0, 0);

    // ---- phase1: tiles 0..14 (issue t+1, phase1)
    #pragma unroll 1
    for (int t = 0; t < 15; ++t) {
        const int sl = t & 1, nx = sl ^ 1;
        KSTEP(sl, I0_1(t + 1, nx), "4", I1_1(t + 1, nx), I2_1(t + 1, nx), 2);
    }
    // ---- bridge: compute tile 15 (phase1), issue tile 16 (phase2, k2=0)
    KSTEP(1, I0_2(0, 0), "4", I1_2(0, 0), I2_2(0, 0), 2);
    // ---- phase2: tiles 16..18 (issue k2 = t-15)
    #pragma unroll 1
    for (int t = 16; t < 19; ++t) {
        const int sl = t & 1, nx = sl ^ 1;
        KSTEP(sl, I0_2(t - 15, nx), "4", I1_2(t - 15, nx), I2_2(t - 15, nx), 3);
    }
    // ---- peel: tile 19, drain
    KSTEP(1, ((void)0), "0", ((void)0), ((void)0), 3);

    // ---- gate epilogue (h read as bf16)
    const int rq = (lane >> 4) * 4;
    #pragma unroll
    for (int n = 0; n < 2; ++n) {
        const int hcol = hcb + wn * 32 + n * 16 + fr;   // 0..2047
        const int lcol = hcol & 255;                    // within diagonal block
        const float bir0 = b_ir_lin[hcol]        + b_ir[hcol];
        const float bir1 = b_ir_lin[2048 + hcol] + b_ir[2048 + hcol];
        const float bir2 = b_ir_lin[4096 + hcol] + b_ir[4096 + hcol];
        const float bhr0 = b_hr[kb * 768 + lcol];
        const float bhr1 = b_hr[kb * 768 + 256 + lcol];
        const float bhr2 = b_hr[kb * 768 + 512 + lcol];
        #pragma unroll
        for (int mi = 0; mi < 4; ++mi) {
            #pragma unroll
            for (int r = 0; r < 4; ++r) {
                const int row = bm + wm * 64 + mi * 16 + rq + r;
                const float pr = acc[0][mi][n][r] + bir0 + bhr0;
                const float pz = acc[1][mi][n][r] + bir1 + bhr1;
                const float xn = acc[2][mi][n][r] + bir2;
                const float hn = acc[3][mi][n][r] + bhr2;
                const float rg = sigmoidf_(pr);
                const float zg = sigmoidf_(pz);
                const float ng = tanhf_(xn + rg * hn);
                const float hv = bf2f(Hbb[(size_t)row * H + hcol]);
                out[(size_t)row * H + hcol] = (1.0f - zg) * hv + zg * ng;
            }
        }
    }
}

// ---------------------------------------------------------------- launch
extern "C" void kernel_launch(void* const* d_in, const int* in_sizes, int n_in,
                              void* d_out, int out_size, void* d_ws, size_t ws_size,
                              hipStream_t stream) {
    const float* x        = (const float*)d_in[0];
    const float* h        = (const float*)d_in[1];
    const float* W_ir     = (const float*)d_in[2];
    const float* b_ir_lin = (const float*)d_in[3];
    const float* b_ir     = (const float*)d_in[4];
    const float* W_h      = (const float*)d_in[5];
    const float* b_hr     = (const float*)d_in[6];
    float* out = (float*)d_out;

    char* ws = (char*)d_ws;
    unsigned short* xb   = (unsigned short*)(ws);               // 16 MiB
    unsigned short* wirb = (unsigned short*)(ws + 16777216);    // 12 MiB
    unsigned short* hb   = (unsigned short*)(ws + 29360128);    // 32 MiB
    unsigned short* whb  = (unsigned short*)(ws + 62914560);    //  3 MiB

    cast_all<<<32256, 256, 0, stream>>>(x, W_ir, h, W_h, xb, wirb, hb, whb);

    gru_fused<<<2048, 256, 0, stream>>>(xb, wirb, hb, whb,
                                        b_ir_lin, b_ir, b_hr, out);
}

// Round 8
// 170.320 us; speedup vs baseline: 1.3569x; 1.0014x over previous
//
#include <hip/hip_runtime.h>
#include <cstdint>
#include <cstddef>

// Block-diagonal GRU on MI355X (gfx950), fully fused bf16 MFMA path.
// B=8192, IN=1024, H=2048, NB=8, BS=256, 3H=6144.
// One kernel computes wx (K=1024) AND wh (K=256, block-diagonal) for a
// 128x64 h-column tile, then applies the GRU gates in the epilogue.
// Geometry: 256 thr (4 waves 2Mx2N), BM=128, BK=64, LDS 80 KiB -> 2 blocks/CU.
// K-step (minimum-sync): vmcnt(0) | ONE barrier | issue 10 stages (other
// slot) | 20 ds_read_b128 + 48 MFMA compiler-scheduled (counted lgkm, no
// explicit drains/fences). Stage(t) has ~1 full K-tile of slack at the wait.

typedef __attribute__((ext_vector_type(8))) short bf16x8;
typedef __attribute__((ext_vector_type(4))) float f32x4;

__device__ __forceinline__ unsigned short f2bf(float f) {
    uint32_t u = __float_as_uint(f);
    u += 0x7FFFu + ((u >> 16) & 1u);   // round-to-nearest-even
    return (unsigned short)(u >> 16);
}
__device__ __forceinline__ float bf2f(unsigned short b) {
    return __uint_as_float(((uint32_t)b) << 16);
}

__device__ __forceinline__ void gload16(const void* g, void* l) {
    __builtin_amdgcn_global_load_lds(
        (const __attribute__((address_space(1))) void*)g,
        (__attribute__((address_space(3))) void*)l,
        16, 0, 0);
}

__device__ __forceinline__ float sigmoidf_(float x) {
    return 1.0f / (1.0f + __expf(-x));
}
__device__ __forceinline__ float tanhf_(float x) {
    float e = __expf(-2.0f * fabsf(x));
    float t = (1.0f - e) / (1.0f + e);
    return copysignf(t, x);
}

// ---------------------------------------------------------------- one cast
// regions (in float4 units): x 2097152 | W_ir 1572864 | h 4194304 | W_h 393216
__global__ __launch_bounds__(256)
void cast_all(const float* __restrict__ x, const float* __restrict__ wir,
              const float* __restrict__ h, const float* __restrict__ wh,
              unsigned short* __restrict__ xb, unsigned short* __restrict__ wirb,
              unsigned short* __restrict__ hb, unsigned short* __restrict__ whb) {
    const int i = blockIdx.x * 256 + threadIdx.x;
    const float* s; unsigned short* d; int j;
    if (i < 2097152)      { s = x;   d = xb;   j = i; }
    else if (i < 3670016) { s = wir; d = wirb; j = i - 2097152; }
    else if (i < 7864320) { s = h;   d = hb;   j = i - 3670016; }
    else                  { s = wh;  d = whb;  j = i - 7864320; }
    const float4 v = *reinterpret_cast<const float4*>(s + (size_t)j * 4);
    ushort4 o;
    o.x = f2bf(v.x); o.y = f2bf(v.y); o.z = f2bf(v.z); o.w = f2bf(v.w);
    *reinterpret_cast<ushort4*>(d + (size_t)j * 4) = o;
}

// ---------------------------------------------------------------- fused GRU
// acc groups: 0=r(sum of both GEMMs), 1=z(sum), 2=wxn, 3=whn.
// NT = 2 during phase1 (x @ W_ir^T), 3 during phase2 (hb @ W_h[kb]^T).
// A tile 128x64 (4 chunks of 32 rows), B tile 192x64 (6 chunks).
// Issues/thread/K-tile: 10, all at once right after the barrier.
// LDS rows 128 B, T2 XOR-swizzle byte^=(row&7)<<4 via inverse-swizzled
// global source (linear gload_lds dest) + swizzled ds_read (G21).

#define MFMA24(NT) do {                                                        \
    _Pragma("unroll")                                                          \
    for (int m_ = 0; m_ < 4; ++m_) {                                           \
        acc[0][m_][0] = __builtin_amdgcn_mfma_f32_16x16x32_bf16(               \
            av[m_], bv[0][0], acc[0][m_][0], 0, 0, 0);                         \
        acc[0][m_][1] = __builtin_amdgcn_mfma_f32_16x16x32_bf16(               \
            av[m_], bv[0][1], acc[0][m_][1], 0, 0, 0);                         \
        acc[1][m_][0] = __builtin_amdgcn_mfma_f32_16x16x32_bf16(               \
            av[m_], bv[1][0], acc[1][m_][0], 0, 0, 0);                         \
        acc[1][m_][1] = __builtin_amdgcn_mfma_f32_16x16x32_bf16(               \
            av[m_], bv[1][1], acc[1][m_][1], 0, 0, 0);                         \
        acc[NT][m_][0] = __builtin_amdgcn_mfma_f32_16x16x32_bf16(              \
            av[m_], bv[2][0], acc[NT][m_][0], 0, 0, 0);                        \
        acc[NT][m_][1] = __builtin_amdgcn_mfma_f32_16x16x32_bf16(              \
            av[m_], bv[2][1], acc[NT][m_][1], 0, 0, 0);                        \
    }                                                                          \
} while (0)

#define LDA(m, kb_) (*(const bf16x8*)(aS + (wm * 64 + (m) * 16 + fr) * 64 + (kb_)))
#define LDB(s, n_, kb_) (*(const bf16x8*)(bS + ((s) * 64 + wn * 32 + (n_) * 16 + fr) * 64 + (kb_)))

// full stage of one K-tile (10 gloads), phase1 (kt along K=1024)
#define I_1(kt, ds) do {                                                       \
    gload16(b1[0] + (size_t)(kt) * 64, Bs + (ds) * 12288 + 0 * 2048 + doff);   \
    gload16(b1[1] + (size_t)(kt) * 64, Bs + (ds) * 12288 + 1 * 2048 + doff);   \
    gload16(b1[2] + (size_t)(kt) * 64, Bs + (ds) * 12288 + 2 * 2048 + doff);   \
    gload16(b1[3] + (size_t)(kt) * 64, Bs + (ds) * 12288 + 3 * 2048 + doff);   \
    gload16(b1[4] + (size_t)(kt) * 64, Bs + (ds) * 12288 + 4 * 2048 + doff);   \
    gload16(b1[5] + (size_t)(kt) * 64, Bs + (ds) * 12288 + 5 * 2048 + doff);   \
    gload16(a1[0] + (size_t)(kt) * 64, As + (ds) * 8192 + 0 * 2048 + doff);    \
    gload16(a1[1] + (size_t)(kt) * 64, As + (ds) * 8192 + 1 * 2048 + doff);    \
    gload16(a1[2] + (size_t)(kt) * 64, As + (ds) * 8192 + 2 * 2048 + doff);    \
    gload16(a1[3] + (size_t)(kt) * 64, As + (ds) * 8192 + 3 * 2048 + doff); } while (0)
// full stage, phase2 (k2 along K=256)
#define I_2(k2, ds) do {                                                       \
    gload16(b2[0] + (size_t)(k2) * 64, Bs + (ds) * 12288 + 0 * 2048 + doff);   \
    gload16(b2[1] + (size_t)(k2) * 64, Bs + (ds) * 12288 + 1 * 2048 + doff);   \
    gload16(b2[2] + (size_t)(k2) * 64, Bs + (ds) * 12288 + 2 * 2048 + doff);   \
    gload16(b2[3] + (size_t)(k2) * 64, Bs + (ds) * 12288 + 3 * 2048 + doff);   \
    gload16(b2[4] + (size_t)(k2) * 64, Bs + (ds) * 12288 + 4 * 2048 + doff);   \
    gload16(b2[5] + (size_t)(k2) * 64, Bs + (ds) * 12288 + 5 * 2048 + doff);   \
    gload16(a2[0] + (size_t)(k2) * 64, As + (ds) * 8192 + 0 * 2048 + doff);    \
    gload16(a2[1] + (size_t)(k2) * 64, As + (ds) * 8192 + 1 * 2048 + doff);    \
    gload16(a2[2] + (size_t)(k2) * 64, As + (ds) * 8192 + 2 * 2048 + doff);    \
    gload16(a2[3] + (size_t)(k2) * 64, As + (ds) * 8192 + 3 * 2048 + doff); } while (0)

// One K-tile, minimum sync. ISSUE targets slot_^1 — its previous readers
// all finished before this barrier (their reads were in body t-1, and the
// barrier orders body(t-1) reads before body(t) issues).
#define KSTEP(slot_, ISSUE, NT) do {                                           \
    asm volatile("s_waitcnt vmcnt(0)" ::: "memory");                           \
    __builtin_amdgcn_s_barrier();                                              \
    ISSUE;                                                                     \
    const unsigned short* aS = As + (slot_) * 8192;                            \
    const unsigned short* bS = Bs + (slot_) * 12288;                           \
    _Pragma("unroll") for (int m_ = 0; m_ < 4; ++m_) av[m_] = LDA(m_, kb0);    \
    _Pragma("unroll") for (int s_ = 0; s_ < 3; ++s_) {                         \
        bv[s_][0] = LDB(s_, 0, kb0); bv[s_][1] = LDB(s_, 1, kb0); }            \
    MFMA24(NT);                                                                \
    _Pragma("unroll") for (int m_ = 0; m_ < 4; ++m_) av[m_] = LDA(m_, kb1);    \
    _Pragma("unroll") for (int s_ = 0; s_ < 3; ++s_) {                         \
        bv[s_][0] = LDB(s_, 0, kb1); bv[s_][1] = LDB(s_, 1, kb1); }            \
    MFMA24(NT);                                                                \
} while (0)

__global__ __launch_bounds__(256, 2)
void gru_fused(const unsigned short* __restrict__ Xb,    // [8192][1024] bf16
               const unsigned short* __restrict__ Wirb,  // [6144][1024] bf16
               const unsigned short* __restrict__ Hbb,   // [8192][2048] bf16
               const unsigned short* __restrict__ Whb,   // [8][768][256] bf16
               const float* __restrict__ b_ir_lin,       // [6144]
               const float* __restrict__ b_ir,           // [6144]
               const float* __restrict__ b_hr,           // [6144]
               float* __restrict__ out) {                // [8192][2048] f32
    constexpr int K1 = 1024, H = 2048;
    __shared__ unsigned short lds[2 * 8192 + 2 * 12288];   // 80 KiB
    unsigned short* const As = lds;
    unsigned short* const Bs = lds + 2 * 8192;

    const int tid  = threadIdx.x;
    const int lane = tid & 63;
    const int w    = tid >> 6;   // 0..3
    const int wm   = w >> 1;     // 0..1 (64-row half)
    const int wn   = w & 1;      // 0..1 (32-col half)

    // Grid: 2048 = 8 kb (XCD-exclusive) x 64 bm x 4 hsub (hsub innermost).
    const int bid  = blockIdx.x;
    const int kb   = bid & 7;
    const int idx  = bid >> 3;          // 0..255
    const int bm   = (idx >> 2) * 128;
    const int hsub = idx & 3;
    const int hcb  = kb * 256 + hsub * 64;   // h-column base

    // ---- staging sources (inverse-swizzled global, linear LDS dest)
    const int srow  = tid >> 3;                 // 0..31 (row within 32-row chunk)
    const int chunk = (tid & 7) ^ (srow & 7);   // T2 XOR involution
    const int scol  = chunk * 8;
    const int doff  = tid * 8;                  // element offset within a chunk
    const unsigned short* a1[4];
    const unsigned short* a2[4];
    #pragma unroll
    for (int q = 0; q < 4; ++q) {
        a1[q] = Xb  + (size_t)(bm + q * 32 + srow) * K1 + scol;
        a2[q] = Hbb + (size_t)(bm + q * 32 + srow) * H + kb * 256 + scol;
    }
    const unsigned short* b1[6];
    const unsigned short* b2[6];
    #pragma unroll
    for (int q = 0; q < 6; ++q) {
        const int s  = q >> 1;
        const int rr = (q & 1) * 32 + srow;
        b1[q] = Wirb + (size_t)(s * 2048 + hcb + rr) * K1 + scol;
        b2[q] = Whb + (size_t)kb * 196608 + (size_t)(s * 256 + hsub * 64 + rr) * 256 + scol;
    }

    // ---- fragment read offsets (swizzled reads, rows are 128 B)
    const int fr  = lane & 15;
    const int k0e = (lane >> 4) * 8;
    const int mfr = (fr & 7) << 4;
    const int kb0 = ((k0e * 2) ^ mfr) >> 1;
    const int kb1 = (((k0e * 2) + 64) ^ mfr) >> 1;

    f32x4 acc[4][4][2] = {};   // [group][m-frag][n-frag]
    bf16x8 av[4], bv[3][2];

    // ---- prologue: stage tile 0 into slot 0 (phase1)
    I_1(0, 0);

    // ---- phase1: tiles 0..14 (stage t+1, phase1)
    #pragma unroll 1
    for (int t = 0; t < 15; ++t) {
        const int sl = t & 1, nx = sl ^ 1;
        KSTEP(sl, I_1(t + 1, nx), 2);
    }
    // ---- bridge: compute tile 15 (phase1), stage tile 16 (phase2, k2=0)
    KSTEP(1, I_2(0, 0), 2);
    // ---- phase2: tiles 16..18 (stage k2 = t-15)
    #pragma unroll 1
    for (int t = 16; t < 19; ++t) {
        const int sl = t & 1, nx = sl ^ 1;
        KSTEP(sl, I_2(t - 15, nx), 3);
    }
    // ---- peel: tile 19, nothing left to stage
    KSTEP(1, ((void)0), 3);

    // ---- gate epilogue (h read as bf16)
    const int rq = (lane >> 4) * 4;
    #pragma unroll
    for (int n = 0; n < 2; ++n) {
        const int hcol = hcb + wn * 32 + n * 16 + fr;   // 0..2047
        const int lcol = hcol & 255;                    // within diagonal block
        const float bir0 = b_ir_lin[hcol]        + b_ir[hcol];
        const float bir1 = b_ir_lin[2048 + hcol] + b_ir[2048 + hcol];
        const float bir2 = b_ir_lin[4096 + hcol] + b_ir[4096 + hcol];
        const float bhr0 = b_hr[kb * 768 + lcol];
        const float bhr1 = b_hr[kb * 768 + 256 + lcol];
        const float bhr2 = b_hr[kb * 768 + 512 + lcol];
        #pragma unroll
        for (int mi = 0; mi < 4; ++mi) {
            #pragma unroll
            for (int r = 0; r < 4; ++r) {
                const int row = bm + wm * 64 + mi * 16 + rq + r;
                const float pr = acc[0][mi][n][r] + bir0 + bhr0;
                const float pz = acc[1][mi][n][r] + bir1 + bhr1;
                const float xn = acc[2][mi][n][r] + bir2;
                const float hn = acc[3][mi][n][r] + bhr2;
                const float rg = sigmoidf_(pr);
                const float zg = sigmoidf_(pz);
                const float ng = tanhf_(xn + rg * hn);
                const float hv = bf2f(Hbb[(size_t)row * H + hcol]);
                out[(size_t)row * H + hcol] = (1.0f - zg) * hv + zg * ng;
            }
        }
    }
}

// ---------------------------------------------------------------- launch
extern "C" void kernel_launch(void* const* d_in, const int* in_sizes, int n_in,
                              void* d_out, int out_size, void* d_ws, size_t ws_size,
                              hipStream_t stream) {
    const float* x        = (const float*)d_in[0];
    const float* h        = (const float*)d_in[1];
    const float* W_ir     = (const float*)d_in[2];
    const float* b_ir_lin = (const float*)d_in[3];
    const float* b_ir     = (const float*)d_in[4];
    const float* W_h      = (const float*)d_in[5];
    const float* b_hr     = (const float*)d_in[6];
    float* out = (float*)d_out;

    char* ws = (char*)d_ws;
    unsigned short* xb   = (unsigned short*)(ws);               // 16 MiB
    unsigned short* wirb = (unsigned short*)(ws + 16777216);    // 12 MiB
    unsigned short* hb   = (unsigned short*)(ws + 29360128);    // 32 MiB
    unsigned short* whb  = (unsigned short*)(ws + 62914560);    //  3 MiB

    cast_all<<<32256, 256, 0, stream>>>(x, W_ir, h, W_h, xb, wirb, hb, whb);

    gru_fused<<<2048, 256, 0, stream>>>(xb, wirb, hb, whb,
                                        b_ir_lin, b_ir, b_hr, out);
}